// Round 3
// baseline (95.339 us; speedup 1.0000x reference)
//
#include <hip/hip_runtime.h>
#include <math.h>

#define CCH   192
#define RCH   48
#define NB    16
#define HW    9216    // 96*96
#define BCTOT (NB*CCH) // 3072

// ---------------------------------------------------------------------------
// Kernel 1: per-(b,c) plane -> avg, max, 3x3 pooled means
// One block per (b,c). Each pooled 32x32 block = 256 float4 = exactly blockDim.
// ---------------------------------------------------------------------------
__global__ __launch_bounds__(256) void k_stats(const float* __restrict__ x,
                                               float* __restrict__ avg,
                                               float* __restrict__ mx,
                                               float* __restrict__ pooled)
{
    int bc = blockIdx.x;
    const float4* p4 = (const float4*)(x + (size_t)bc * HW);
    int t = threadIdx.x;
    float ps[9];
    float m = -INFINITY;
#pragma unroll
    for (int k = 0; k < 9; ++k) {
        int kr = k / 3, kc = k % 3;
        int row = kr * 32 + (t >> 3);
        int wq  = kc * 8  + (t & 7);
        float4 v = p4[row * 24 + wq];
        ps[k] = v.x + v.y + v.z + v.w;
        m = fmaxf(m, fmaxf(fmaxf(v.x, v.y), fmaxf(v.z, v.w)));
    }
#pragma unroll
    for (int off = 32; off > 0; off >>= 1) {
#pragma unroll
        for (int k = 0; k < 9; ++k) ps[k] += __shfl_down(ps[k], off);
        m = fmaxf(m, __shfl_down(m, off));
    }
    __shared__ float red[4][10];
    int wid = t >> 6, lane = t & 63;
    if (lane == 0) {
#pragma unroll
        for (int k = 0; k < 9; ++k) red[wid][k] = ps[k];
        red[wid][9] = m;
    }
    __syncthreads();
    if (t == 0) {
        float tot = 0.f;
#pragma unroll
        for (int k = 0; k < 9; ++k) {
            float pk = red[0][k] + red[1][k] + red[2][k] + red[3][k];
            pooled[bc * 9 + k] = pk * (1.0f / 1024.0f);
            tot += pk;
        }
        float mm = fmaxf(fmaxf(red[0][9], red[1][9]),
                         fmaxf(red[2][9], red[3][9]));
        avg[bc] = tot * (1.0f / (float)HW);
        mx[bc]  = mm;
    }
}

// ---------------------------------------------------------------------------
// Kernel 2 (merged): per-batch theta + h (kept in LDS) + per-(c,k) softmax
// weights. One block per batch.
// ---------------------------------------------------------------------------
__global__ __launch_bounds__(256) void k_coeff(
    const float* __restrict__ avg, const float* __restrict__ mx,
    const float* __restrict__ pooled,
    const float* __restrict__ cam_w1, const float* __restrict__ cam_w2,
    const float* __restrict__ proj_w1,
    const float* __restrict__ bn_gamma, const float* __restrict__ bn_beta,
    const float* __restrict__ proj_w2, const float* __restrict__ adk,
    float* __restrict__ theta, float* __restrict__ wgt)
{
    int b = blockIdx.x;
    int t = threadIdx.x;
    __shared__ float s_av[CCH], s_mx[CCH], s_pool[CCH * 9];
    __shared__ float s_h1p[96], s_h1[RCH], s_hh[RCH * 9];
    if (t < CCH) { s_av[t] = avg[b * CCH + t]; s_mx[t] = mx[b * CCH + t]; }
    for (int i = t; i < CCH * 9; i += 256) s_pool[i] = pooled[b * CCH * 9 + i];
    __syncthreads();
    if (t < 96) {
        int r = t % 48, sel = t / 48;
        const float* src = sel ? s_mx : s_av;
        const float* w = cam_w1 + r * CCH;
        float acc = 0.f;
        for (int c = 0; c < CCH; ++c) acc += src[c] * w[c];
        s_h1p[sel * 48 + r] = fmaxf(acc, 0.f);
    }
    __syncthreads();
    if (t < RCH) s_h1[t] = s_h1p[t] + s_h1p[48 + t];
    __syncthreads();
    if (t < CCH) {
        const float* w = cam_w2 + t * RCH;
        float acc = 0.f;
        for (int r = 0; r < RCH; ++r) acc += s_h1[r] * w[r];
        theta[b * CCH + t] = 1.0f / (1.0f + expf(-acc));
    }
    float bn_s = 1.0f / sqrtf(1.0f + 1e-5f);
    for (int i = t; i < RCH * 9; i += 256) {
        int r = i / 9, k = i % 9;
        const float* w = proj_w1 + r * CCH;
        float acc = 0.f;
        for (int c = 0; c < CCH; ++c) acc += s_pool[c * 9 + k] * w[c];
        float val = acc * (bn_gamma[r] * bn_s) + bn_beta[r];
        s_hh[i] = fmaxf(val, 0.f);
    }
    __syncthreads();
    // phase 2: weights (softmax over G=4)
    for (int i = t; i < CCH * 9; i += 256) {
        int c = i / 9, k = i % 9;
        float sg[4];
#pragma unroll
        for (int g = 0; g < 4; ++g) {
            const float* w = proj_w2 + (size_t)(g * CCH + c) * RCH;
            float acc = 0.f;
            for (int r = 0; r < RCH; ++r) acc += s_hh[r * 9 + k] * w[r];
            sg[g] = acc;
        }
        float mxv = fmaxf(fmaxf(sg[0], sg[1]), fmaxf(sg[2], sg[3]));
        float e[4];
        float sum = 0.f;
#pragma unroll
        for (int g = 0; g < 4; ++g) { e[g] = expf(sg[g] - mxv); sum += e[g]; }
        float inv = 1.0f / sum;
        float acc = 0.f;
#pragma unroll
        for (int g = 0; g < 4; ++g)
            acc += (e[g] * inv) * adk[(size_t)(g * CCH + c) * 9 + k];
        wgt[b * CCH * 9 + i] = acc;
    }
}

// ---------------------------------------------------------------------------
// Kernel 3: depthwise 3x3 conv (pad 1). ONE WAVE PER PLANE.
// lane = rg*8 + cs: 8 row-strips (12 rows) x 8 col-strips (12 floats = 3 f4).
// Halo columns come from neighbor lanes via shfl; row-span boundaries align
// exactly with cs==0/7 image-edge predicates (no unpredicated wave-edge shfl).
// ---------------------------------------------------------------------------
__global__ __launch_bounds__(256) void k_conv(
    const float* __restrict__ x, const float* __restrict__ wgt,
    const float* __restrict__ theta, float* __restrict__ out)
{
    int t = threadIdx.x;
    int wid = t >> 6, lane = t & 63;
    int plane = blockIdx.x * 4 + wid;
    int rg = lane >> 3, cs = lane & 7;
    int rbase = rg * 12 - 1;

    float wr[9];
    float wsum = 0.f;
#pragma unroll
    for (int k = 0; k < 9; ++k) { wr[k] = wgt[plane * 9 + k]; wsum += wr[k]; }
    float th = theta[plane];
    wr[4] = wr[4] * (1.f + th) - wsum;   // fold theta-center adjustment

    const float4* p4 = (const float4*)(x + (size_t)plane * HW);
    float4* o4p = (float4*)(out + (size_t)plane * HW);

    float acc[3][12];
#pragma unroll
    for (int i = 0; i <= 13; ++i) {
        int r = rbase + i;
        bool inr = (r >= 0) && (r < 96);
        float4 a0, a1, a2;
        if (inr) {
            const float4* prow = p4 + r * 24 + cs * 3;
            a0 = prow[0]; a1 = prow[1]; a2 = prow[2];
        } else {
            a0 = make_float4(0.f, 0.f, 0.f, 0.f);
            a1 = a0; a2 = a0;
        }
        float lv = __shfl_up(a2.w, 1);
        float rv = __shfl_down(a0.x, 1);
        float w[14];
        w[0] = (cs == 0) ? 0.f : lv;
        w[1] = a0.x; w[2] = a0.y; w[3] = a0.z; w[4] = a0.w;
        w[5] = a1.x; w[6] = a1.y; w[7] = a1.z; w[8] = a1.w;
        w[9] = a2.x; w[10] = a2.y; w[11] = a2.z; w[12] = a2.w;
        w[13] = (cs == 7) ? 0.f : rv;

        if (i <= 11) {
#pragma unroll
            for (int j = 0; j < 12; ++j)
                acc[i % 3][j] = wr[0] * w[j] + wr[1] * w[j + 1] + wr[2] * w[j + 2];
        }
        if (i >= 1 && i <= 12) {
#pragma unroll
            for (int j = 0; j < 12; ++j)
                acc[(i - 1) % 3][j] += wr[3] * w[j] + wr[4] * w[j + 1] + wr[5] * w[j + 2];
        }
        if (i >= 2) {
            const int s = (i - 2) % 3;
#pragma unroll
            for (int j = 0; j < 12; ++j)
                acc[s][j] += wr[6] * w[j] + wr[7] * w[j + 1] + wr[8] * w[j + 2];
            int orow = rbase + i - 1;      // = rg*12 + (i-2)
            float4* od = o4p + orow * 24 + cs * 3;
            od[0] = make_float4(acc[s][0], acc[s][1], acc[s][2], acc[s][3]);
            od[1] = make_float4(acc[s][4], acc[s][5], acc[s][6], acc[s][7]);
            od[2] = make_float4(acc[s][8], acc[s][9], acc[s][10], acc[s][11]);
        }
    }
}

extern "C" void kernel_launch(void* const* d_in, const int* in_sizes, int n_in,
                              void* d_out, int out_size, void* d_ws, size_t ws_size,
                              hipStream_t stream) {
    const float* x        = (const float*)d_in[0];
    const float* cam_w1   = (const float*)d_in[1];
    const float* cam_w2   = (const float*)d_in[2];
    const float* proj_w1  = (const float*)d_in[3];
    const float* bn_gamma = (const float*)d_in[4];
    const float* bn_beta  = (const float*)d_in[5];
    const float* proj_w2  = (const float*)d_in[6];
    const float* adk      = (const float*)d_in[7];
    float* out = (float*)d_out;
    float* ws  = (float*)d_ws;

    float* avg    = ws;            // 3072
    float* mx     = ws + 3072;     // 3072
    float* pooled = ws + 6144;     // 27648
    float* theta  = ws + 33792;    // 3072
    float* wgt    = ws + 36864;    // 27648

    k_stats <<<BCTOT, 256, 0, stream>>>(x, avg, mx, pooled);
    k_coeff <<<NB,    256, 0, stream>>>(avg, mx, pooled, cam_w1, cam_w2,
                                        proj_w1, bn_gamma, bn_beta,
                                        proj_w2, adk, theta, wgt);
    k_conv  <<<BCTOT / 4, 256, 0, stream>>>(x, wgt, theta, out);
}

// Round 4
// 94.178 us; speedup vs baseline: 1.0123x; 1.0123x over previous
//
#include <hip/hip_runtime.h>
#include <math.h>

#define CCH   192
#define RCH   48
#define NB    16
#define HW    9216    // 96*96
#define BCTOT (NB*CCH) // 3072

// ---------------------------------------------------------------------------
// Kernel 1: per-(b,c) plane -> avg, max, 3x3 pooled means
// One block per (b,c). Each pooled 32x32 block = 256 float4 = exactly blockDim.
// ---------------------------------------------------------------------------
__global__ __launch_bounds__(256) void k_stats(const float* __restrict__ x,
                                               float* __restrict__ avg,
                                               float* __restrict__ mx,
                                               float* __restrict__ pooled)
{
    int bc = blockIdx.x;
    const float4* p4 = (const float4*)(x + (size_t)bc * HW);
    int t = threadIdx.x;
    float ps[9];
    float m = -INFINITY;
#pragma unroll
    for (int k = 0; k < 9; ++k) {
        int kr = k / 3, kc = k % 3;
        int row = kr * 32 + (t >> 3);
        int wq  = kc * 8  + (t & 7);
        float4 v = p4[row * 24 + wq];
        ps[k] = v.x + v.y + v.z + v.w;
        m = fmaxf(m, fmaxf(fmaxf(v.x, v.y), fmaxf(v.z, v.w)));
    }
#pragma unroll
    for (int off = 32; off > 0; off >>= 1) {
#pragma unroll
        for (int k = 0; k < 9; ++k) ps[k] += __shfl_down(ps[k], off);
        m = fmaxf(m, __shfl_down(m, off));
    }
    __shared__ float red[4][10];
    int wid = t >> 6, lane = t & 63;
    if (lane == 0) {
#pragma unroll
        for (int k = 0; k < 9; ++k) red[wid][k] = ps[k];
        red[wid][9] = m;
    }
    __syncthreads();
    if (t == 0) {
        float tot = 0.f;
#pragma unroll
        for (int k = 0; k < 9; ++k) {
            float pk = red[0][k] + red[1][k] + red[2][k] + red[3][k];
            pooled[bc * 9 + k] = pk * (1.0f / 1024.0f);
            tot += pk;
        }
        float mm = fmaxf(fmaxf(red[0][9], red[1][9]),
                         fmaxf(red[2][9], red[3][9]));
        avg[bc] = tot * (1.0f / (float)HW);
        mx[bc]  = mm;
    }
}

// ---------------------------------------------------------------------------
// Kernel 2 (merged): per-batch theta + h (kept in LDS) + per-(c,k) softmax
// weights. One block per batch.
// ---------------------------------------------------------------------------
__global__ __launch_bounds__(256) void k_coeff(
    const float* __restrict__ avg, const float* __restrict__ mx,
    const float* __restrict__ pooled,
    const float* __restrict__ cam_w1, const float* __restrict__ cam_w2,
    const float* __restrict__ proj_w1,
    const float* __restrict__ bn_gamma, const float* __restrict__ bn_beta,
    const float* __restrict__ proj_w2, const float* __restrict__ adk,
    float* __restrict__ theta, float* __restrict__ wgt)
{
    int b = blockIdx.x;
    int t = threadIdx.x;
    __shared__ float s_av[CCH], s_mx[CCH], s_pool[CCH * 9];
    __shared__ float s_h1p[96], s_h1[RCH], s_hh[RCH * 9];
    if (t < CCH) { s_av[t] = avg[b * CCH + t]; s_mx[t] = mx[b * CCH + t]; }
    for (int i = t; i < CCH * 9; i += 256) s_pool[i] = pooled[b * CCH * 9 + i];
    __syncthreads();
    if (t < 96) {
        int r = t % 48, sel = t / 48;
        const float* src = sel ? s_mx : s_av;
        const float* w = cam_w1 + r * CCH;
        float acc = 0.f;
        for (int c = 0; c < CCH; ++c) acc += src[c] * w[c];
        s_h1p[sel * 48 + r] = fmaxf(acc, 0.f);
    }
    __syncthreads();
    if (t < RCH) s_h1[t] = s_h1p[t] + s_h1p[48 + t];
    __syncthreads();
    if (t < CCH) {
        const float* w = cam_w2 + t * RCH;
        float acc = 0.f;
        for (int r = 0; r < RCH; ++r) acc += s_h1[r] * w[r];
        theta[b * CCH + t] = 1.0f / (1.0f + expf(-acc));
    }
    float bn_s = 1.0f / sqrtf(1.0f + 1e-5f);
    for (int i = t; i < RCH * 9; i += 256) {
        int r = i / 9, k = i % 9;
        const float* w = proj_w1 + r * CCH;
        float acc = 0.f;
        for (int c = 0; c < CCH; ++c) acc += s_pool[c * 9 + k] * w[c];
        float val = acc * (bn_gamma[r] * bn_s) + bn_beta[r];
        s_hh[i] = fmaxf(val, 0.f);
    }
    __syncthreads();
    for (int i = t; i < CCH * 9; i += 256) {
        int c = i / 9, k = i % 9;
        float sg[4];
#pragma unroll
        for (int g = 0; g < 4; ++g) {
            const float* w = proj_w2 + (size_t)(g * CCH + c) * RCH;
            float acc = 0.f;
            for (int r = 0; r < RCH; ++r) acc += s_hh[r * 9 + k] * w[r];
            sg[g] = acc;
        }
        float mxv = fmaxf(fmaxf(sg[0], sg[1]), fmaxf(sg[2], sg[3]));
        float e[4];
        float sum = 0.f;
#pragma unroll
        for (int g = 0; g < 4; ++g) { e[g] = expf(sg[g] - mxv); sum += e[g]; }
        float inv = 1.0f / sum;
        float acc = 0.f;
#pragma unroll
        for (int g = 0; g < 4; ++g)
            acc += (e[g] * inv) * adk[(size_t)(g * CCH + c) * 9 + k];
        wgt[b * CCH * 9 + i] = acc;
    }
}

// ---------------------------------------------------------------------------
// Kernel 3: depthwise 3x3 conv (pad 1). One WAVE per HALF-plane (48 rows).
// 64 lanes = 8 rowgroups (6 output rows each) x 8 col-lanes. Lane cs owns
// INTERLEAVED float4 columns {cs, cs+8, cs+16} so every load/store has 8
// consecutive lanes on 128B contiguous memory. Column halos via shuffles:
// shfl_up/down(1) for interior lanes; within-rowgroup broadcasts for the
// cs==0/7 seam lanes; image edges predicated to zero.
// ---------------------------------------------------------------------------
__global__ __launch_bounds__(256) void k_conv(
    const float* __restrict__ x, const float* __restrict__ wgt,
    const float* __restrict__ theta, float* __restrict__ out)
{
    int t = threadIdx.x;
    int wid = t >> 6, lane = t & 63;
    int plane = blockIdx.x * 2 + (wid >> 1);
    int half  = wid & 1;
    int rgL = lane >> 3, cs = lane & 7;
    int rbase = half * 48 + rgL * 6 - 1;
    int lane7 = (lane & 56) | 7;   // last lane of this rowgroup
    int lane0 = (lane & 56);       // first lane of this rowgroup

    float wr[9];
    float wsum = 0.f;
#pragma unroll
    for (int k = 0; k < 9; ++k) { wr[k] = wgt[plane * 9 + k]; wsum += wr[k]; }
    float th = theta[plane];
    wr[4] = wr[4] * (1.f + th) - wsum;   // fold theta-center adjustment

    const float4* p4 = (const float4*)(x + (size_t)plane * HW);
    float4* o4p = (float4*)(out + (size_t)plane * HW);

    float acc[3][3][4];   // [rot-slot][j-block][col] — all indices compile-time
#pragma unroll
    for (int i = 0; i < 8; ++i) {
        int r = rbase + i;
        bool inr = (r >= 0) && (r < 96);
        float4 a0, a1, a2;
        if (inr) {
            const float4* prow = p4 + r * 24 + cs;
            a0 = prow[0]; a1 = prow[8]; a2 = prow[16];
        } else {
            a0 = make_float4(0.f, 0.f, 0.f, 0.f);
            a1 = a0; a2 = a0;
        }
        // interior halos
        float lw0 = __shfl_up(a0.w, 1), lw1 = __shfl_up(a1.w, 1), lw2 = __shfl_up(a2.w, 1);
        float rw0 = __shfl_down(a0.x, 1), rw1 = __shfl_down(a1.x, 1), rw2 = __shfl_down(a2.x, 1);
        // seam broadcasts (within rowgroup)
        float lb1 = __shfl(a0.w, lane7, 64);
        float lb2 = __shfl(a1.w, lane7, 64);
        float rb0 = __shfl(a1.x, lane0, 64);
        float rb1 = __shfl(a2.x, lane0, 64);
        float w6[3][6];
        w6[0][0] = (cs == 0) ? 0.f : lw0;
        w6[1][0] = (cs == 0) ? lb1 : lw1;
        w6[2][0] = (cs == 0) ? lb2 : lw2;
        w6[0][5] = (cs == 7) ? rb0 : rw0;
        w6[1][5] = (cs == 7) ? rb1 : rw1;
        w6[2][5] = (cs == 7) ? 0.f : rw2;
        w6[0][1] = a0.x; w6[0][2] = a0.y; w6[0][3] = a0.z; w6[0][4] = a0.w;
        w6[1][1] = a1.x; w6[1][2] = a1.y; w6[1][3] = a1.z; w6[1][4] = a1.w;
        w6[2][1] = a2.x; w6[2][2] = a2.y; w6[2][3] = a2.z; w6[2][4] = a2.w;

        if (i <= 5) {               // top tap for output row r+1
#pragma unroll
            for (int j = 0; j < 3; ++j)
#pragma unroll
                for (int c = 0; c < 4; ++c)
                    acc[i % 3][j][c] = wr[0] * w6[j][c] + wr[1] * w6[j][c + 1] + wr[2] * w6[j][c + 2];
        }
        if (i >= 1 && i <= 6) {     // mid tap for output row r
#pragma unroll
            for (int j = 0; j < 3; ++j)
#pragma unroll
                for (int c = 0; c < 4; ++c)
                    acc[(i - 1) % 3][j][c] += wr[3] * w6[j][c] + wr[4] * w6[j][c + 1] + wr[5] * w6[j][c + 2];
        }
        if (i >= 2) {               // bottom tap for output row r-1 -> store
            const int s = (i - 2) % 3;
#pragma unroll
            for (int j = 0; j < 3; ++j)
#pragma unroll
                for (int c = 0; c < 4; ++c)
                    acc[s][j][c] += wr[6] * w6[j][c] + wr[7] * w6[j][c + 1] + wr[8] * w6[j][c + 2];
            int orow = rbase + i - 1;
            float4* od = o4p + orow * 24 + cs;
            od[0]  = make_float4(acc[s][0][0], acc[s][0][1], acc[s][0][2], acc[s][0][3]);
            od[8]  = make_float4(acc[s][1][0], acc[s][1][1], acc[s][1][2], acc[s][1][3]);
            od[16] = make_float4(acc[s][2][0], acc[s][2][1], acc[s][2][2], acc[s][2][3]);
        }
    }
}

extern "C" void kernel_launch(void* const* d_in, const int* in_sizes, int n_in,
                              void* d_out, int out_size, void* d_ws, size_t ws_size,
                              hipStream_t stream) {
    const float* x        = (const float*)d_in[0];
    const float* cam_w1   = (const float*)d_in[1];
    const float* cam_w2   = (const float*)d_in[2];
    const float* proj_w1  = (const float*)d_in[3];
    const float* bn_gamma = (const float*)d_in[4];
    const float* bn_beta  = (const float*)d_in[5];
    const float* proj_w2  = (const float*)d_in[6];
    const float* adk      = (const float*)d_in[7];
    float* out = (float*)d_out;
    float* ws  = (float*)d_ws;

    float* avg    = ws;            // 3072
    float* mx     = ws + 3072;     // 3072
    float* pooled = ws + 6144;     // 27648
    float* theta  = ws + 33792;    // 3072
    float* wgt    = ws + 36864;    // 27648

    k_stats <<<BCTOT, 256, 0, stream>>>(x, avg, mx, pooled);
    k_coeff <<<NB,    256, 0, stream>>>(avg, mx, pooled, cam_w1, cam_w2,
                                        proj_w1, bn_gamma, bn_beta,
                                        proj_w2, adk, theta, wgt);
    k_conv  <<<BCTOT / 2, 256, 0, stream>>>(x, wgt, theta, out);
}